// Round 19
// baseline (55.791 us; speedup 1.0000x reference)
//
#include <hip/hip_runtime.h>

// ConvDatapath: bit-serial crossbar conv with per-chunk ADC quantization.
// SINGLE FUSED KERNEL (one graph node — R1..R18 data shows a ~18.6us
// per-kernel-node floor; 2 nodes pinned us at ~37). 784 blocks x 512 thr:
// block = (rtile 0..391, chalf 0..1). Pre-barrier: 32 lane-groups quantize
// 2 w-rows each (this chalf's 64 rows) into scrW; waves 0-3 also quantize
// the 16 x-rows (direct global loads) into scrX. One barrier. Phase D =
// R11 k_d: 8 waves = 4 ctiles x 2 khalf, MFMA+ADC, pacc combine, epilogue.
// All value-producing op sequences identical to reference (absmax 0.75).
// Nx = 6272, Ny = 128, K = 576 (5 chunks of 116, padded to 128).

#define KDIM  576
#define NPB   116
#define SSTR  688    // scratch row stride: 43*16 -> b128-aligned, 172 dw % 32 = 12

typedef int i32x4 __attribute__((ext_vector_type(4)));
typedef float f32x4 __attribute__((ext_vector_type(4)));

__device__ __forceinline__ i32x4 slice2b(i32x4 v, int sh) {
    i32x4 r;
    r[0] = (int)(((unsigned)v[0] >> sh) & 0x03030303u);
    r[1] = (int)(((unsigned)v[1] >> sh) & 0x03030303u);
    r[2] = (int)(((unsigned)v[2] >> sh) & 0x03030303u);
    r[3] = (int)(((unsigned)v[3] >> sh) & 0x03030303u);
    return r;
}

// quantize one row spread over a 16-lane group (lane i16 holds k=36*i16..+35,
// k-ordered). Stats via 4-step shuffle (exact); 9 dword-aligned b32 writes,
// col = k + 12*chunk (i.e. chunk*128 + k%116).
__device__ __forceinline__ void quant36(const float (&v)[36], unsigned char* rowp,
                                        int i16, float* sc, float* of,
                                        float* sm_, int sidx)
{
    float mn = v[0], mx = v[0], sm = 0.f;
#pragma unroll
    for (int m = 0; m < 36; m++) { mn = fminf(mn, v[m]); mx = fmaxf(mx, v[m]); sm += v[m]; }
#pragma unroll
    for (int off = 1; off < 16; off <<= 1) {
        mn = fminf(mn, __shfl_xor(mn, off));
        mx = fmaxf(mx, __shfl_xor(mx, off));
        sm += __shfl_xor(sm, off);
    }
    float step = (mx - mn) / 255.0f;
    if (i16 == 0) { sc[sidx] = step; of[sidx] = mn; sm_[sidx] = sm; }
    int k0 = i16 * 36;
#pragma unroll
    for (int d = 0; d < 9; d++) {
        unsigned int dw = 0;
#pragma unroll
        for (int mb = 0; mb < 4; mb++) {
            int q = (int)rintf((v[d * 4 + mb] - mn) / step);
            q = q < 0 ? 0 : (q > 255 ? 255 : q);
            dw |= (unsigned)q << (8 * mb);
        }
        int kd = k0 + d * 4;
        int ch = kd / NPB;
        *(unsigned int*)(rowp + kd + 12 * ch) = dw;
    }
}

// zero the K-pad dwords of scratch row (idx>>4), pad dword (idx&15)
__device__ __forceinline__ void zero_pad_row(unsigned char* scr, int idx) {
    int rl = idx >> 4, dwp = idx & 15;
    int col = dwp < 12 ? (dwp / 3) * 128 + 116 + (dwp % 3) * 4
                       : 624 + (dwp - 12) * 4;
    *(unsigned int*)(scr + rl * SSTR + col) = 0u;
}

__global__ __launch_bounds__(512) void k_fused(
    const float* __restrict__ x, const float* __restrict__ w,
    float* __restrict__ out)
{
    __shared__ __align__(16) unsigned char scrX[16 * SSTR];   // 11,008 B
    __shared__ __align__(16) unsigned char scrW[64 * SSTR];   // 44,032 B
    __shared__ __align__(16) int pacc[4][64][4];              // 4,096 B
    __shared__ float xscl[16], xofl[16], xsml[16];
    __shared__ float wscl[64], wofl[64], wsml[64];

    int tid = threadIdx.x, wv = tid >> 6, lane = tid & 63;
    int g = lane >> 4, i16 = lane & 15;
    int blk = blockIdx.x;                 // 0..783
    int rtile = blk >> 1, chalf = blk & 1;
    int b = rtile >= 196 ? 1 : 0;
    int pos0 = (rtile - 196 * b) * 16;
    const float* xb = x + (size_t)(b * 64) * 3136;

    // ---- pads (disjoint columns from quant writes; no race)
    if (tid < 256) zero_pad_row(scrX, tid);
    for (int j = tid; j < 1024; j += 512) zero_pad_row(scrW, j);

    // ---- w-quant: 32 lane-groups x 2 rows = this chalf's 64 rows
    {
        int grp = wv * 4 + g;             // 0..31
#pragma unroll
        for (int q = 0; q < 2; q++) {
            int rl = grp * 2 + q;         // local w row 0..63
            int row = chalf * 64 + rl;    // global w row
            const float* wr = w + (size_t)row * KDIM + i16 * 36;
            float v[36];
#pragma unroll
            for (int d = 0; d < 9; d++) {
                f32x4 t = *(const f32x4*)(wr + d * 4);
                v[d*4+0] = t[0]; v[d*4+1] = t[1]; v[d*4+2] = t[2]; v[d*4+3] = t[3];
            }
            quant36(v, scrW + rl * SSTR, i16, wscl, wofl, wsml, rl);
        }
    }

    // ---- x-quant: waves 0..3, one row per lane-group (direct global loads)
    if (wv < 4) {
        int i = wv * 4 + g;               // tile-local row 0..15
        int pos = pos0 + i;
        int hg = pos / 56, wg = pos - hg * 56;
        float v[36];
#pragma unroll
        for (int j = 0; j < 4; j++) {
            const float* cb = xb + (size_t)(i16 * 4 + j) * 3136;
#pragma unroll
            for (int kh = 0; kh < 3; kh++) {
                int r = hg - 1 + kh;
                bool rok = (r >= 0 && r < 56);
#pragma unroll
                for (int kw = 0; kw < 3; kw++) {
                    int c = wg - 1 + kw;
                    bool ok = rok && c >= 0 && c < 56;
                    v[j * 9 + kh * 3 + kw] = ok ? cb[r * 56 + c] : 0.f;
                }
            }
        }
        quant36(v, scrX + i * SSTR, i16, xscl, xofl, xsml, i);
    }
    __syncthreads();

    // ---- phase D: wave = (ctl_l = wv>>1, khalf = wv&1); ctile = chalf*4+ctl_l
    // khalf0: chunks 0-2; khalf1: chunks 3-4 + combine + epilogue.
    // X frag: scrX row i16, col ch*128 + ks*64 + g*16 (R8-proven).
    // W frag: scrW row ctl_l*16+i16, same cols (R10-proven).
    int ctl_l = wv >> 1, khalf = wv & 1;
    const unsigned char* xp = scrX + i16 * SSTR + g * 16;
    const unsigned char* wp = scrW + (ctl_l * 16 + i16) * SSTR + g * 16;

    const i32x4 zero = {0, 0, 0, 0};
    i32x4 acc4[4] = {{0,0,0,0},{0,0,0,0},{0,0,0,0},{0,0,0,0}};
    int cbeg = khalf ? 3 : 0, cend = khalf ? 5 : 3;

    for (int ch = cbeg; ch < cend; ch++) {
        i32x4 x0 = *(const i32x4*)(xp + ch * 128);
        i32x4 x1 = *(const i32x4*)(xp + ch * 128 + 64);
        i32x4 w0 = *(const i32x4*)(wp + ch * 128);
        i32x4 w1 = *(const i32x4*)(wp + ch * 128 + 64);
        i32x4 ws0[4], ws1[4];
#pragma unroll
        for (int ws = 0; ws < 4; ws++) {
            ws0[ws] = slice2b(w0, 6 - 2 * ws);
            ws1[ws] = slice2b(w1, 6 - 2 * ws);
        }
#pragma unroll
        for (int is = 0; is < 4; is++) {
            int ish = 6 - 2 * is;
            i32x4 a0 = slice2b(x0, ish), a1 = slice2b(x1, ish);
#pragma unroll
            for (int ws = 0; ws < 4; ws++) {
                i32x4 d = __builtin_amdgcn_mfma_i32_16x16x64_i8(ws0[ws], a0, zero, 0, 0, 0);
                d = __builtin_amdgcn_mfma_i32_16x16x64_i8(ws1[ws], a1, d, 0, 0, 0);
                int sh = ish + 6 - 2 * ws;
#pragma unroll
                for (int r = 0; r < 4; r++) {
                    int z = d[r];
                    z = z > 1024 ? 1024 : z;                 // ADC clip (z >= 0)
                    int t = (z >> 2) & 1;
                    int r4 = (z + 1 + t) & ~3;               // round-half-even, mult of 4
                    acc4[ws][r] += r4 << sh;                 // 2^(ish+wsh)
                }
            }
        }
    }

    i32x4 acc;
#pragma unroll
    for (int r = 0; r < 4; r++)
        acc[r] = (acc4[0][r] + acc4[1][r]) + (acc4[2][r] + acc4[3][r]);  // exact

    if (khalf == 0) *(i32x4*)&pacc[ctl_l][lane][0] = acc;
    __syncthreads();

    if (khalf == 1) {
        i32x4 p = *(const i32x4*)&pacc[ctl_l][lane][0];
#pragma unroll
        for (int r = 0; r < 4; r++) acc[r] += p[r];      // chunk-sum, exact

        // epilogue: D[row = w-row (g*4+r), col = x-row (i16)]; 64B coalesced
        float xs_ = xscl[i16], xo = xofl[i16], xsv = xsml[i16];
        int hw = pos0 + i16;
#pragma unroll
        for (int r = 0; r < 4; r++) {
            int rl = ctl_l * 16 + g * 4 + r;             // local w row
            int wrow = chalf * 64 + rl;
            float tt = ((float)acc[r] * xs_) * wscl[rl];
            float res = ((tt + xo * wsml[rl]) + wofl[rl] * xsv)
                      - (xo * wofl[rl]) * 576.0f;
            out[(size_t)(b * 128 + wrow) * 3136 + hw] = res;
        }
    }
}

extern "C" void kernel_launch(void* const* d_in, const int* in_sizes, int n_in,
                              void* d_out, int out_size, void* d_ws, size_t ws_size,
                              hipStream_t stream) {
    const float* x = (const float*)d_in[0];   // [2][64][56][56]
    const float* w = (const float*)d_in[1];   // [128][64][3][3]
    float* out = (float*)d_out;               // [2][128][56][56]

    hipLaunchKernelGGL(k_fused, dim3(784), dim3(512), 0, stream, x, w, out);
}